// Round 3
// baseline (485.460 us; speedup 1.0000x reference)
//
#include <hip/hip_runtime.h>

typedef unsigned short u16;
typedef __attribute__((ext_vector_type(8))) short bf16x8;    // 8 bf16 in 4 VGPRs
typedef __attribute__((ext_vector_type(16))) float f32x16;   // 32x32 accumulator

__device__ __forceinline__ u16 f2bf(float f) {
    unsigned u = __float_as_uint(f);
    u += 0x7fffu + ((u >> 16) & 1u);   // round-to-nearest-even
    return (u16)(u >> 16);
}

__device__ __forceinline__ void g2l16(const void* g, void* l) {
    __builtin_amdgcn_global_load_lds((const __attribute__((address_space(1))) void*)g,
                                     (__attribute__((address_space(3))) void*)l, 16, 0, 0);
}

// ---------------------------------------------------------------------------
// GEMM: C[M,N] = alpha * A[M,K] @ B^T  where B is stored [N,K] row-major.
// bf16 in, fp32 accum. 128x128 tile, BK=64, 4 waves x (2x2 of 32x32x16 MFMA).
// XOR chunk swizzle on the GLOBAL source side -> conflict-free LDS layout
// (SQ_LDS_BANK_CONFLICT == 0 measured in rounds 1-2 with this structure).
// mode 0: plain grid.
// mode 1: packed lower-triangle grid (blockIdx.x -> (bx,by), bx<=by). score GEMM.
// mode 2: by reversed (longest K first) + K capped at (by+1)*128. a@v GEMM.
// ---------------------------------------------------------------------------
#define BM 128
#define BN 128
#define BK 64

template <bool OUT_BF16>
__global__ __launch_bounds__(256, 4) void gemm_bt(
    const u16* __restrict__ A, const u16* __restrict__ B, void* __restrict__ Cout,
    int K, int lda, int ldb, int ldc,
    long long sA, long long sB, long long sC,
    float alpha, int mode)
{
    int bx, by;
    const int bz = blockIdx.z;
    if (mode == 1) {                       // packed triangle: l -> (bx<=by, by)
        int l = blockIdx.x;
        by = (int)((sqrtf(8.f * (float)l + 1.f) - 1.f) * 0.5f);
        while ((by + 1) * (by + 2) / 2 <= l) ++by;
        while (by * (by + 1) / 2 > l) --by;
        bx = l - by * (by + 1) / 2;
    } else if (mode == 2) {                // reversed by, causal K cap
        bx = blockIdx.x; by = (int)gridDim.y - 1 - (int)blockIdx.y;
    } else {
        bx = blockIdx.x; by = blockIdx.y;
    }
    int Keff = K;
    if (mode == 2) { int cap = (by + 1) * BM; if (cap < Keff) Keff = cap; }

    __shared__ alignas(16) u16 As[BM * BK];
    __shared__ alignas(16) u16 Bs[BN * BK];

    const int tid  = threadIdx.x;
    const int wave = tid >> 6, lane = tid & 63;
    const int wm = wave >> 1, wn = wave & 1;
    const int l5 = lane >> 5, r31 = lane & 31;

    const u16* Ab = A + sA * bz + (size_t)(by * BM) * lda;
    const u16* Bb = B + sB * bz + (size_t)(bx * BN) * ldb;

    // kt-invariant staging pointers (advance by BK elements per tile)
    const u16* ap[4]; const u16* bp[4]; int sb[4];
#pragma unroll
    for (int j = 0; j < 4; ++j) {
        int s   = (wave * 4 + j) * 64 + lane;
        int row = s >> 3;
        int cc  = (s & 7) ^ (row & 7);     // slot s holds global chunk cc of row
        ap[j] = Ab + (size_t)row * lda + cc * 8;
        bp[j] = Bb + (size_t)row * ldb + cc * 8;
        sb[j] = (wave * 4 + j) * 64;
    }

    f32x16 acc[2][2] = {};

    const int kiters = Keff / BK;
    for (int kt = 0; kt < kiters; ++kt) {
#pragma unroll
        for (int j = 0; j < 4; ++j) { g2l16(ap[j], As + (size_t)sb[j] * 8); ap[j] += BK; }
#pragma unroll
        for (int j = 0; j < 4; ++j) { g2l16(bp[j], Bs + (size_t)sb[j] * 8); bp[j] += BK; }
        __syncthreads();
#pragma unroll
        for (int ks = 0; ks < 4; ++ks) {   // four 16-wide k-steps per tile
            bf16x8 af[2], bfv[2];
#pragma unroll
            for (int i = 0; i < 2; ++i) {
                int mr = wm * 64 + i * 32 + r31;
                int cc = (ks * 2 + l5) ^ (mr & 7);
                af[i] = *(const bf16x8*)(As + mr * BK + cc * 8);
            }
#pragma unroll
            for (int i = 0; i < 2; ++i) {
                int nr = wn * 64 + i * 32 + r31;
                int cc = (ks * 2 + l5) ^ (nr & 7);
                bfv[i] = *(const bf16x8*)(Bs + nr * BK + cc * 8);
            }
#pragma unroll
            for (int i = 0; i < 2; ++i)
#pragma unroll
                for (int jn = 0; jn < 2; ++jn)
                    acc[i][jn] = __builtin_amdgcn_mfma_f32_32x32x16_bf16(
                        af[i], bfv[jn], acc[i][jn], 0, 0, 0);
        }
        __syncthreads();
    }

    // epilogue: 32x32 C/D layout col=lane&31, row=(reg&3)+8*(reg>>2)+4*(lane>>5)
#pragma unroll
    for (int i = 0; i < 2; ++i) {
        int rowb = by * BM + wm * 64 + i * 32 + 4 * l5;
#pragma unroll
        for (int jn = 0; jn < 2; ++jn) {
            int col = bx * BN + wn * 64 + jn * 32 + r31;
            if constexpr (OUT_BF16) {
                u16* Cp = (u16*)Cout + sC * bz;
#pragma unroll
                for (int reg = 0; reg < 16; ++reg) {
                    int row = rowb + (reg & 3) + 8 * (reg >> 2);
                    Cp[(size_t)row * ldc + col] = f2bf(acc[i][jn][reg] * alpha);
                }
            } else {
                float* Cp = (float*)Cout + sC * bz;
#pragma unroll
                for (int reg = 0; reg < 16; ++reg) {
                    int row = rowb + (reg & 3) + 8 * (reg >> 2);
                    Cp[(size_t)row * ldc + col] = acc[i][jn][reg] * alpha;
                }
            }
        }
    }
}

// fp32 -> bf16 elementwise cast (x). Exact grid: n/1024 blocks.
__global__ void cast_f32_bf16(const float4* __restrict__ in, ushort4* __restrict__ out) {
    int i = blockIdx.x * 256 + threadIdx.x;
    float4 f = in[i];
    ushort4 o;
    o.x = f2bf(f.x); o.y = f2bf(f.y); o.z = f2bf(f.z); o.w = f2bf(f.w);
    out[i] = o;
}

// transpose + cast: in fp32 [R][Cc] -> out bf16 [Cc][R]  (weights, small)
__global__ void transpose_cast_f32(const float* __restrict__ in, u16* __restrict__ out,
                                   int R, int Cc) {
    __shared__ u16 tile[32][33];
    int tx = threadIdx.x, ty = threadIdx.y;
    int c0 = blockIdx.x * 32, r0 = blockIdx.y * 32;
#pragma unroll
    for (int k = 0; k < 4; ++k)
        tile[ty + k * 8][tx] = f2bf(in[(size_t)(r0 + ty + k * 8) * Cc + c0 + tx]);
    __syncthreads();
#pragma unroll
    for (int k = 0; k < 4; ++k)
        out[(size_t)(c0 + ty + k * 8) * R + r0 + tx] = tile[tx][ty + k * 8];
}

// vectorized bf16 transpose, 64x64 tile, ushort4 (8B) global access both sides.
// in [R][Cc] rowstride ldin -> out [Cc][R] rowstride ldout, batched over z.
__global__ __launch_bounds__(256) void transpose_bf16_v(
    const u16* __restrict__ in, u16* __restrict__ out,
    int ldin, int ldout, long long sIn, long long sOut)
{
    __shared__ u16 tile[64][68];           // +4 u16 pad
    in  += (long long)blockIdx.z * sIn;
    out += (long long)blockIdx.z * sOut;
    const int tid = threadIdx.x;
    const int tx = tid & 15, ty = tid >> 4;      // 16 x 16
    const int c0 = blockIdx.x * 64, r0 = blockIdx.y * 64;
#pragma unroll
    for (int k = 0; k < 4; ++k)                  // load rows r0+ty+16k
        *(ushort4*)&tile[ty + 16 * k][4 * tx] =
            *(const ushort4*)&in[(size_t)(r0 + ty + 16 * k) * ldin + c0 + 4 * tx];
    __syncthreads();
#pragma unroll
    for (int k = 0; k < 4; ++k) {                // write out rows c0+ty+16k
        int c = ty + 16 * k;
        ushort4 o;
        o.x = tile[4 * tx + 0][c];
        o.y = tile[4 * tx + 1][c];
        o.z = tile[4 * tx + 2][c];
        o.w = tile[4 * tx + 3][c];
        *(ushort4*)&out[(size_t)(c0 + c) * ldout + r0 + 4 * tx] = o;
    }
}

// In-place causal softmax, one WAVE per row. Reads the fp32 score row S[t][:],
// writes bf16 probabilities over the same bytes (row stride stays T fp32 =
// 2T bf16). Only reads cols [0, t]; writes/zero-fills [0, roundup128(t+1))
// which is exactly what the kcap'd a@v GEMM consumes.
__global__ __launch_bounds__(256) void softmax_causal_ip(
    float* __restrict__ S, int T, long long sS)
{
    const int wave = threadIdx.x >> 6, lane = threadIdx.x & 63;
    const int t = blockIdx.x * 4 + wave;
    float* row = S + (long long)blockIdx.y * sS + (size_t)t * T;
    const int n = t + 1;
    const int L = (n + 127) & ~127;        // kcap'd row length (multiple of 128)
    const int nit = (L + 255) >> 8;        // chunks of 64 lanes x 4 floats, <=8

    float v[32];
    float m = -1e30f;
    for (int it = 0; it < nit; ++it) {
        int c = it * 64 + lane;
        int e = c * 4;
        float4 f = make_float4(-1e30f, -1e30f, -1e30f, -1e30f);
        if (e < n) f = ((const float4*)row)[c];
        v[it * 4 + 0] = (e + 0 < n) ? f.x : -1e30f;
        v[it * 4 + 1] = (e + 1 < n) ? f.y : -1e30f;
        v[it * 4 + 2] = (e + 2 < n) ? f.z : -1e30f;
        v[it * 4 + 3] = (e + 3 < n) ? f.w : -1e30f;
        m = fmaxf(m, fmaxf(fmaxf(v[it * 4 + 0], v[it * 4 + 1]),
                           fmaxf(v[it * 4 + 2], v[it * 4 + 3])));
    }
    for (int off = 32; off > 0; off >>= 1) m = fmaxf(m, __shfl_xor(m, off));

    float s = 0.f;
    for (int it = 0; it < nit; ++it) {
#pragma unroll
        for (int j = 0; j < 4; ++j) {
            v[it * 4 + j] = __expf(v[it * 4 + j] - m);
            s += v[it * 4 + j];
        }
    }
    for (int off = 32; off > 0; off >>= 1) s += __shfl_xor(s, off);
    float inv = 1.f / s;

    u16* orow = (u16*)row;
    for (int it = 0; it < nit; ++it) {
        int c = it * 64 + lane;
        if (c * 4 < L) {
            ushort4 o;
            o.x = f2bf(v[it * 4 + 0] * inv);
            o.y = f2bf(v[it * 4 + 1] * inv);
            o.z = f2bf(v[it * 4 + 2] * inv);
            o.w = f2bf(v[it * 4 + 3] * inv);
            ((ushort4*)orow)[c] = o;
        }
    }
}

extern "C" void kernel_launch(void* const* d_in, const int* in_sizes, int n_in,
                              void* d_out, int out_size, void* d_ws, size_t ws_size,
                              hipStream_t stream)
{
    const float* x     = (const float*)d_in[0];
    const float* Wqkv  = (const float*)d_in[1];
    const float* Wproj = (const float*)d_in[2];
    float* out = (float*)d_out;

    const int Bb = 8, T = 2048, C1 = 1024, C3 = 3072;

    // workspace layout (bytes) — attnb overlays xb (dead after qkv GEMM);
    // bf16 A overlays fp32 S in place (row stride T fp32 = 2T bf16).
    char* ws = (char*)d_ws;
    u16*  xb     = (u16*)(ws);                       //  32 MB  x bf16 [B*T, C]
    u16*  attnb  = (u16*)(ws);                       //  32 MB  overlay (post-qkv)
    u16*  WqkvT  = (u16*)(ws +  33554432ULL);        //   6 MB  [3C, C]
    u16*  WprojT = (u16*)(ws +  39845888ULL);        //   2 MB  [C, C]
    u16*  qkvb   = (u16*)(ws +  41943040ULL);        //  96 MB  [B*T, 3C]
    u16*  vT     = (u16*)(ws + 142606336ULL);        //  32 MB  [B][C, T]
    float* Sbuf  = (float*)(ws + 176160768ULL);      //  z*16 MB scores / probs

    // largest batch-chunk whose score buffer fits the workspace
    int zc = 1;
    if      (ws_size >= 176160768ULL + 8ULL * 16777216ULL) zc = 8;
    else if (ws_size >= 176160768ULL + 4ULL * 16777216ULL) zc = 4;
    else if (ws_size >= 176160768ULL + 2ULL * 16777216ULL) zc = 2;

    // 1. cast x -> bf16   (16.7M elems, exact grid)
    cast_f32_bf16<<<16384, 256, 0, stream>>>((const float4*)x, (ushort4*)xb);

    // 2. transpose+cast weights
    transpose_cast_f32<<<dim3(96, 32), dim3(32, 8), 0, stream>>>(Wqkv,  WqkvT,  C1, C3);
    transpose_cast_f32<<<dim3(32, 32), dim3(32, 8), 0, stream>>>(Wproj, WprojT, C1, C1);

    // 3. qkv = x @ Wqkv   [16384,1024]x[1024,3072] -> bf16 [16384,3072]
    gemm_bt<true><<<dim3(24, 128, 1), 256, 0, stream>>>(
        xb, WqkvT, qkvb, C1, C1, C1, C3, 0, 0, 0, 1.0f, 0);

    // 4. vT[b][c][s] = v[b][s][c]   (v = qkv cols [2C,3C))
    transpose_bf16_v<<<dim3(16, 32, 8), 256, 0, stream>>>(
        qkvb + 2 * C1, vT, C3, T, (long long)T * C3, (long long)C1 * T);

    // 5. attention, zc batches at a time
    for (int i = 0; i < Bb; i += zc) {
        const u16* qb  = qkvb + (long long)i * T * C3;
        const u16* kb  = qb + C1;
        const u16* vtb = vT + (long long)i * C1 * T;
        u16* ab = attnb + (long long)i * T * C1;

        // S = (q @ k^T) * C^-0.5, fp32, packed lower-triangle grid (136/batch)
        gemm_bt<false><<<dim3(136, 1, zc), 256, 0, stream>>>(
            qb, kb, Sbuf, C1, C3, C3, T,
            (long long)T * C3, (long long)T * C3, (long long)T * T,
            0.03125f, 1);

        // A = causal softmax(S), bf16 in place, zero-filled to roundup128(t+1)
        softmax_causal_ip<<<dim3(T / 4, zc), 256, 0, stream>>>(
            Sbuf, T, (long long)T * T);

        // attn = A @ v  (A bf16 rows at stride 2T; B^T = vT [C,T]), K kcap'd,
        // by reversed so longest-K blocks dispatch first
        gemm_bt<true><<<dim3(8, 16, zc), 256, 0, stream>>>(
            (const u16*)Sbuf, vtb, ab, T, 2 * T, T, C1,
            2LL * T * T, (long long)C1 * T, (long long)T * C1,
            1.0f, 2);
    }

    // 6. out = attn @ Wproj  -> fp32 d_out
    gemm_bt<false><<<dim3(8, 128, 1), 256, 0, stream>>>(
        attnb, WprojT, out, C1, C1, C1, C1, 0, 0, 0, 1.0f, 0);

    (void)in_sizes; (void)n_in; (void)out_size;
}

// Round 4
// 462.730 us; speedup vs baseline: 1.0491x; 1.0491x over previous
//
#include <hip/hip_runtime.h>

typedef unsigned short u16;
typedef __attribute__((ext_vector_type(8))) short bf16x8;   // 8 bf16 in 4 VGPRs
typedef __attribute__((ext_vector_type(4))) float f32x4;

__device__ __forceinline__ u16 f2bf(float f) {
    unsigned u = __float_as_uint(f);
    u += 0x7fffu + ((u >> 16) & 1u);   // round-to-nearest-even
    return (u16)(u >> 16);
}

__device__ __forceinline__ void g2l16(const void* g, void* l) {
    __builtin_amdgcn_global_load_lds((const __attribute__((address_space(1))) void*)g,
                                     (__attribute__((address_space(3))) void*)l, 16, 0, 0);
}

// ---------------------------------------------------------------------------
// GEMM: C[M,N] = alpha * A[M,K] @ B^T  where B is stored [N,K] row-major.
// bf16 in, fp32 accum. 128x128 tile, BK=64, 4 waves x (4x4 of 16x16x32 MFMA).
// NOTE: MFMA shape is 16x16x32 deliberately — the 32x32x16 variant's fragment
// reads xor only by lane>>5, making lanes L and L+16 alias the same bank group
// (4-way => 1.26e7 SQ_LDS_BANK_CONFLICT, qkv 103->122us, round 3). This
// pattern (xor includes lane>>4) measured 0 conflicts in rounds 1-2.
// mode 0: plain grid.
// mode 1: packed lower-triangle grid (blockIdx.x -> (bx,by), bx<=by). score GEMM.
// mode 2: by reversed (longest K first) + K capped at (by+1)*128. final GEMM.
// ---------------------------------------------------------------------------
#define BM 128
#define BN 128
#define BK 64

template <bool OUT_BF16>
__global__ __launch_bounds__(256, 4) void gemm_bt(
    const u16* __restrict__ A, const u16* __restrict__ B, void* __restrict__ Cout,
    int K, int lda, int ldb, int ldc,
    long long sA, long long sB, long long sC,
    float alpha, int mode)
{
    int bx, by;
    const int bz = blockIdx.z;
    if (mode == 1) {                       // packed triangle: l -> (bx<=by, by)
        int l = blockIdx.x;
        by = (int)((sqrtf(8.f * (float)l + 1.f) - 1.f) * 0.5f);
        while ((by + 1) * (by + 2) / 2 <= l) ++by;
        while (by * (by + 1) / 2 > l) --by;
        bx = l - by * (by + 1) / 2;
    } else if (mode == 2) {                // reversed by, causal K cap
        bx = blockIdx.x; by = (int)gridDim.y - 1 - (int)blockIdx.y;
    } else {
        bx = blockIdx.x; by = blockIdx.y;
    }
    int Keff = K;
    if (mode == 2) { int cap = (by + 1) * BM; if (cap < Keff) Keff = cap; }

    __shared__ alignas(16) u16 As[BM * BK];
    __shared__ alignas(16) u16 Bs[BN * BK];

    const int tid  = threadIdx.x;
    const int wave = tid >> 6, lane = tid & 63;
    const int wm = wave >> 1, wn = wave & 1;
    const int q = lane >> 4, r = lane & 15;

    const u16* Ab = A + sA * bz + (size_t)(by * BM) * lda;
    const u16* Bb = B + sB * bz + (size_t)(bx * BN) * ldb;

    // kt-invariant staging pointers (advance by BK elements per tile)
    const u16* ap[4]; const u16* bp[4]; int sb[4];
#pragma unroll
    for (int j = 0; j < 4; ++j) {
        int s   = (wave * 4 + j) * 64 + lane;
        int row = s >> 3;
        int cc  = (s & 7) ^ (row & 7);     // slot s holds global chunk cc of row
        ap[j] = Ab + (size_t)row * lda + cc * 8;
        bp[j] = Bb + (size_t)row * ldb + cc * 8;
        sb[j] = (wave * 4 + j) * 64;
    }

    f32x4 acc[4][4] = {};

    const int kiters = Keff / BK;
    for (int kt = 0; kt < kiters; ++kt) {
#pragma unroll
        for (int j = 0; j < 4; ++j) { g2l16(ap[j], As + (size_t)sb[j] * 8); ap[j] += BK; }
#pragma unroll
        for (int j = 0; j < 4; ++j) { g2l16(bp[j], Bs + (size_t)sb[j] * 8); bp[j] += BK; }
        __syncthreads();
#pragma unroll
        for (int ks = 0; ks < 2; ++ks) {   // two 32-wide k-steps per tile
            bf16x8 af[4], bfv[4];
#pragma unroll
            for (int i = 0; i < 4; ++i) {
                int mr = wm * 64 + i * 16 + r;
                int cc = (ks * 4 + q) ^ (mr & 7);
                af[i] = *(const bf16x8*)(As + mr * BK + cc * 8);
            }
#pragma unroll
            for (int i = 0; i < 4; ++i) {
                int nr = wn * 64 + i * 16 + r;
                int cc = (ks * 4 + q) ^ (nr & 7);
                bfv[i] = *(const bf16x8*)(Bs + nr * BK + cc * 8);
            }
#pragma unroll
            for (int i = 0; i < 4; ++i)
#pragma unroll
                for (int jn = 0; jn < 4; ++jn)
                    acc[i][jn] = __builtin_amdgcn_mfma_f32_16x16x32_bf16(
                        af[i], bfv[jn], acc[i][jn], 0, 0, 0);
        }
        __syncthreads();
    }

    // epilogue: C/D layout col=lane&15, row=(lane>>4)*4+reg
    if constexpr (OUT_BF16) {
        u16* Cp = (u16*)Cout + sC * bz;
#pragma unroll
        for (int i = 0; i < 4; ++i) {
            int rowb = by * BM + wm * 64 + i * 16 + q * 4;
#pragma unroll
            for (int jn = 0; jn < 4; ++jn) {
                int col = bx * BN + wn * 64 + jn * 16 + r;
#pragma unroll
                for (int rr = 0; rr < 4; ++rr)
                    Cp[(size_t)(rowb + rr) * ldc + col] = f2bf(acc[i][jn][rr] * alpha);
            }
        }
    } else {
        float* Cp = (float*)Cout + sC * bz;
#pragma unroll
        for (int i = 0; i < 4; ++i) {
            int rowb = by * BM + wm * 64 + i * 16 + q * 4;
#pragma unroll
            for (int jn = 0; jn < 4; ++jn) {
                int col = bx * BN + wn * 64 + jn * 16 + r;
#pragma unroll
                for (int rr = 0; rr < 4; ++rr)
                    Cp[(size_t)(rowb + rr) * ldc + col] = acc[i][jn][rr] * alpha;
            }
        }
    }
}

// fp32 -> bf16 elementwise cast (x). Exact grid: n/1024 blocks.
__global__ void cast_f32_bf16(const float4* __restrict__ in, ushort4* __restrict__ out) {
    int i = blockIdx.x * 256 + threadIdx.x;
    float4 f = in[i];
    ushort4 o;
    o.x = f2bf(f.x); o.y = f2bf(f.y); o.z = f2bf(f.z); o.w = f2bf(f.w);
    out[i] = o;
}

// transpose + cast: in fp32 [R][Cc] -> out bf16 [Cc][R]  (weights, small)
__global__ void transpose_cast_f32(const float* __restrict__ in, u16* __restrict__ out,
                                   int R, int Cc) {
    __shared__ u16 tile[32][33];
    int tx = threadIdx.x, ty = threadIdx.y;
    int c0 = blockIdx.x * 32, r0 = blockIdx.y * 32;
#pragma unroll
    for (int k = 0; k < 4; ++k)
        tile[ty + k * 8][tx] = f2bf(in[(size_t)(r0 + ty + k * 8) * Cc + c0 + tx]);
    __syncthreads();
#pragma unroll
    for (int k = 0; k < 4; ++k)
        out[(size_t)(c0 + ty + k * 8) * R + r0 + tx] = tile[tx][ty + k * 8];
}

// In-place causal softmax, one WAVE per row. Reads the fp32 score row S[t][:],
// writes bf16 probabilities over the same bytes (row stride stays T fp32 =
// 2T bf16). Only reads cols [0, t]; writes/zero-fills [0, roundup128(t+1))
// which is exactly what the kcap'd final GEMM consumes.
__global__ __launch_bounds__(256) void softmax_causal_ip(
    float* __restrict__ S, int T, long long sS)
{
    const int wave = threadIdx.x >> 6, lane = threadIdx.x & 63;
    const int t = blockIdx.x * 4 + wave;
    float* row = S + (long long)blockIdx.y * sS + (size_t)t * T;
    const int n = t + 1;
    const int L = (n + 127) & ~127;        // kcap'd row length (multiple of 128)
    const int nit = (L + 255) >> 8;        // chunks of 64 lanes x 4 floats, <=8

    float v[32];
    float m = -1e30f;
    for (int it = 0; it < nit; ++it) {
        int c = it * 64 + lane;
        int e = c * 4;
        float4 f = make_float4(-1e30f, -1e30f, -1e30f, -1e30f);
        if (e < n) f = ((const float4*)row)[c];
        v[it * 4 + 0] = (e + 0 < n) ? f.x : -1e30f;
        v[it * 4 + 1] = (e + 1 < n) ? f.y : -1e30f;
        v[it * 4 + 2] = (e + 2 < n) ? f.z : -1e30f;
        v[it * 4 + 3] = (e + 3 < n) ? f.w : -1e30f;
        m = fmaxf(m, fmaxf(fmaxf(v[it * 4 + 0], v[it * 4 + 1]),
                           fmaxf(v[it * 4 + 2], v[it * 4 + 3])));
    }
    for (int off = 32; off > 0; off >>= 1) m = fmaxf(m, __shfl_xor(m, off));

    float s = 0.f;
    for (int it = 0; it < nit; ++it) {
#pragma unroll
        for (int j = 0; j < 4; ++j) {
            v[it * 4 + j] = __expf(v[it * 4 + j] - m);
            s += v[it * 4 + j];
        }
    }
    for (int off = 32; off > 0; off >>= 1) s += __shfl_xor(s, off);
    float inv = 1.f / s;

    u16* orow = (u16*)row;
    for (int it = 0; it < nit; ++it) {
        int c = it * 64 + lane;
        if (c * 4 < L) {
            ushort4 o;
            o.x = f2bf(v[it * 4 + 0] * inv);
            o.y = f2bf(v[it * 4 + 1] * inv);
            o.z = f2bf(v[it * 4 + 2] * inv);
            o.w = f2bf(v[it * 4 + 3] * inv);
            ((ushort4*)orow)[c] = o;
        }
    }
}

extern "C" void kernel_launch(void* const* d_in, const int* in_sizes, int n_in,
                              void* d_out, int out_size, void* d_ws, size_t ws_size,
                              hipStream_t stream)
{
    const float* x     = (const float*)d_in[0];
    const float* Wqkv  = (const float*)d_in[1];
    const float* Wproj = (const float*)d_in[2];
    float* out = (float*)d_out;

    const int Bb = 8, T = 2048, C1 = 1024, C3 = 3072;

    // Reassociation: out = (A@V)@Wp = A@(V@Wp). VWpT[b] = Wp^T @ V^T ([C, T])
    // is computed right after qkv (off the softmax critical path), replacing
    // BOTH the vT transpose and the final proj GEMM.
    //
    // workspace layout (bytes); bf16 probs overlay fp32 S in place.
    char* ws = (char*)d_ws;
    u16*  xb     = (u16*)(ws);                       //  32 MB  x bf16 [B*T, C]
    u16*  WqkvT  = (u16*)(ws +  33554432ULL);        //   6 MB  [3C, C]
    u16*  WprojT = (u16*)(ws +  39845888ULL);        //   2 MB  [C, C]
    u16*  qkvb   = (u16*)(ws +  41943040ULL);        //  96 MB  [B*T, 3C]
    u16*  VWpT   = (u16*)(ws + 142606336ULL);        //  32 MB  [B][C, T]
    float* Sbuf  = (float*)(ws + 176160768ULL);      //  zc*16 MB scores / probs

    // largest batch-chunk whose score buffer fits the workspace
    int zc = 1;
    if      (ws_size >= 176160768ULL + 8ULL * 16777216ULL) zc = 8;
    else if (ws_size >= 176160768ULL + 4ULL * 16777216ULL) zc = 4;
    else if (ws_size >= 176160768ULL + 2ULL * 16777216ULL) zc = 2;

    // 1. cast x -> bf16   (16.7M elems, exact grid)
    cast_f32_bf16<<<16384, 256, 0, stream>>>((const float4*)x, (ushort4*)xb);

    // 2. transpose+cast weights
    transpose_cast_f32<<<dim3(96, 32), dim3(32, 8), 0, stream>>>(Wqkv,  WqkvT,  C1, C3);
    transpose_cast_f32<<<dim3(32, 32), dim3(32, 8), 0, stream>>>(Wproj, WprojT, C1, C1);

    // 3. qkv = x @ Wqkv   [16384,1024]x[1024,3072] -> bf16 [16384,3072]
    gemm_bt<true><<<dim3(24, 128, 1), 256, 0, stream>>>(
        xb, WqkvT, qkvb, C1, C1, C1, C3, 0, 0, 0, 1.0f, 0);

    // 4. VWpT[b] = Wp^T @ V^T : C[M=C1 (c), N=T (s)] = WprojT @ (V rows)^T
    //    B = V rows inside qkvb (ldb = 3C), A = WprojT shared across z.
    gemm_bt<true><<<dim3(16, 8, 8), 256, 0, stream>>>(
        WprojT, qkvb + 2 * C1, VWpT, C1, C1, C3, T,
        0, (long long)T * C3, (long long)C1 * T, 1.0f, 0);

    // 5. attention, zc batches at a time
    for (int i = 0; i < Bb; i += zc) {
        const u16* qb   = qkvb + (long long)i * T * C3;
        const u16* kb   = qb + C1;
        const u16* vwpb = VWpT + (long long)i * C1 * T;
        float* ob = out + (long long)i * T * C1;

        // S = (q @ k^T) * C^-0.5, fp32, packed lower-triangle grid (136/batch)
        gemm_bt<false><<<dim3(136, 1, zc), 256, 0, stream>>>(
            qb, kb, Sbuf, C1, C3, C3, T,
            (long long)T * C3, (long long)T * C3, (long long)T * T,
            0.03125f, 1);

        // A = causal softmax(S), bf16 in place, zero-filled to roundup128(t+1)
        softmax_causal_ip<<<dim3(T / 4, zc), 256, 0, stream>>>(
            Sbuf, T, (long long)T * T);

        // out = A @ (V@Wp)  (A bf16 rows at stride 2T; B^T = VWpT [C,T]),
        // K kcap'd causally, by reversed so longest-K blocks dispatch first
        gemm_bt<false><<<dim3(8, 16, zc), 256, 0, stream>>>(
            (const u16*)Sbuf, vwpb, ob, T, 2 * T, T, C1,
            2LL * T * T, (long long)C1 * T, (long long)T * C1,
            1.0f, 2);
    }

    (void)in_sizes; (void)n_in; (void)out_size;
}

// Round 5
// 434.220 us; speedup vs baseline: 1.1180x; 1.0657x over previous
//
#include <hip/hip_runtime.h>

typedef unsigned short u16;
typedef __attribute__((ext_vector_type(8))) short bf16x8;   // 8 bf16 in 4 VGPRs
typedef __attribute__((ext_vector_type(4))) float f32x4;

__device__ __forceinline__ u16 f2bf(float f) {
    unsigned u = __float_as_uint(f);
    u += 0x7fffu + ((u >> 16) & 1u);   // round-to-nearest-even
    return (u16)(u >> 16);
}

__device__ __forceinline__ void g2l16(const void* g, void* l) {
    __builtin_amdgcn_global_load_lds((const __attribute__((address_space(1))) void*)g,
                                     (__attribute__((address_space(3))) void*)l, 16, 0, 0);
}

// Packed-triangular score layout (per batch, fp32 units):
//   block-row by (rows by*128..by*128+127) has row length L=(by+1)*128 and
//   base P(by) = 16384 * by*(by+1)/2.  Total = 16384*136 = 2,228,224 fp32
//   (8.9 MB/batch vs 16.8 dense) -> zc=8 fits in 204 MB of workspace.
#define SPACK_ELEMS 2228224LL

// ---------------------------------------------------------------------------
// GEMM: C[M,N] = alpha * A[M,K] @ B^T  where B is stored [N,K] row-major.
// bf16 in, fp32 accum. 128x128 tile, BK=64, 4 waves x (4x4 of 16x16x32 MFMA).
// NOTE: MFMA shape is 16x16x32 deliberately — the 32x32x16 variant's fragment
// reads xor only by lane>>5, making lanes L and L+16 alias the same bank group
// (4-way => 1.26e7 SQ_LDS_BANK_CONFLICT, qkv 103->122us, round 3). This
// pattern (xor includes lane>>4) measured 0 conflicts in rounds 1,2,4.
// mode 0: plain grid.
// mode 1: packed lower-triangle grid; C written into packed-triangular S.
// mode 2: by reversed, K capped at (by+1)*128; A read from packed-tri S (bf16).
// ---------------------------------------------------------------------------
#define BM 128
#define BN 128
#define BK 64

template <bool OUT_BF16>
__global__ __launch_bounds__(256, 4) void gemm_bt(
    const u16* __restrict__ A, const u16* __restrict__ B, void* __restrict__ Cout,
    int K, int lda, int ldb, int ldc,
    long long sA, long long sB, long long sC,
    float alpha, int mode)
{
    int bx, by;
    const int bz = blockIdx.z;
    if (mode == 1) {                       // packed triangle: l -> (bx<=by, by)
        int l = blockIdx.x;
        by = (int)((sqrtf(8.f * (float)l + 1.f) - 1.f) * 0.5f);
        while ((by + 1) * (by + 2) / 2 <= l) ++by;
        while (by * (by + 1) / 2 > l) --by;
        bx = l - by * (by + 1) / 2;
    } else if (mode == 2) {                // reversed by, causal K cap
        bx = blockIdx.x; by = (int)gridDim.y - 1 - (int)blockIdx.y;
    } else {
        bx = blockIdx.x; by = blockIdx.y;
    }
    int Keff = K;
    if (mode == 2) { int cap = (by + 1) * BM; if (cap < Keff) Keff = cap; }

    __shared__ alignas(16) u16 As[BM * BK];
    __shared__ alignas(16) u16 Bs[BN * BK];

    const int tid  = threadIdx.x;
    const int wave = tid >> 6, lane = tid & 63;
    const int wm = wave >> 1, wn = wave & 1;
    const int q = lane >> 4, r = lane & 15;

    const long long Pby = 16384LL * (by * (by + 1) / 2);   // packed-tri base

    const u16* Ab;
    int lda_e = lda;
    if (mode == 2) {                       // A rows live in packed S (bf16 view)
        lda_e = 2 * (by + 1) * BM;         // u16 stride = fp32 row size
        Ab = A + sA * bz + 2 * Pby;
    } else {
        Ab = A + sA * bz + (size_t)(by * BM) * lda_e;
    }
    const u16* Bb = B + sB * bz + (size_t)(bx * BN) * ldb;

    // kt-invariant staging pointers (advance by BK elements per tile)
    const u16* ap[4]; const u16* bp[4]; int sb[4];
#pragma unroll
    for (int j = 0; j < 4; ++j) {
        int s   = (wave * 4 + j) * 64 + lane;
        int row = s >> 3;
        int cc  = (s & 7) ^ (row & 7);     // slot s holds global chunk cc of row
        ap[j] = Ab + (size_t)row * lda_e + cc * 8;
        bp[j] = Bb + (size_t)row * ldb + cc * 8;
        sb[j] = (wave * 4 + j) * 64;
    }

    f32x4 acc[4][4] = {};

    const int kiters = Keff / BK;
    for (int kt = 0; kt < kiters; ++kt) {
#pragma unroll
        for (int j = 0; j < 4; ++j) { g2l16(ap[j], As + (size_t)sb[j] * 8); ap[j] += BK; }
#pragma unroll
        for (int j = 0; j < 4; ++j) { g2l16(bp[j], Bs + (size_t)sb[j] * 8); bp[j] += BK; }
        __syncthreads();
#pragma unroll
        for (int ks = 0; ks < 2; ++ks) {   // two 32-wide k-steps per tile
            bf16x8 af[4], bfv[4];
#pragma unroll
            for (int i = 0; i < 4; ++i) {
                int mr = wm * 64 + i * 16 + r;
                int cc = (ks * 4 + q) ^ (mr & 7);
                af[i] = *(const bf16x8*)(As + mr * BK + cc * 8);
            }
#pragma unroll
            for (int i = 0; i < 4; ++i) {
                int nr = wn * 64 + i * 16 + r;
                int cc = (ks * 4 + q) ^ (nr & 7);
                bfv[i] = *(const bf16x8*)(Bs + nr * BK + cc * 8);
            }
#pragma unroll
            for (int i = 0; i < 4; ++i)
#pragma unroll
                for (int jn = 0; jn < 4; ++jn)
                    acc[i][jn] = __builtin_amdgcn_mfma_f32_16x16x32_bf16(
                        af[i], bfv[jn], acc[i][jn], 0, 0, 0);
        }
        __syncthreads();
    }

    // epilogue: C/D layout col=lane&15, row=(lane>>4)*4+reg
    if (mode == 1) {                       // packed-triangular fp32 write
        float* Cp = (float*)Cout + sC * bz + Pby;
        const int ldrow = (by + 1) * BM;
#pragma unroll
        for (int i = 0; i < 4; ++i) {
            int lr = wm * 64 + i * 16 + q * 4;            // local row in block-row
#pragma unroll
            for (int jn = 0; jn < 4; ++jn) {
                int col = bx * BN + wn * 64 + jn * 16 + r; // col < ldrow (bx<=by)
#pragma unroll
                for (int rr = 0; rr < 4; ++rr)
                    Cp[(size_t)(lr + rr) * ldrow + col] = acc[i][jn][rr] * alpha;
            }
        }
    } else if constexpr (OUT_BF16) {
        u16* Cp = (u16*)Cout + sC * bz;
#pragma unroll
        for (int i = 0; i < 4; ++i) {
            int rowb = by * BM + wm * 64 + i * 16 + q * 4;
#pragma unroll
            for (int jn = 0; jn < 4; ++jn) {
                int col = bx * BN + wn * 64 + jn * 16 + r;
#pragma unroll
                for (int rr = 0; rr < 4; ++rr)
                    Cp[(size_t)(rowb + rr) * ldc + col] = f2bf(acc[i][jn][rr] * alpha);
            }
        }
    } else {
        float* Cp = (float*)Cout + sC * bz;
#pragma unroll
        for (int i = 0; i < 4; ++i) {
            int rowb = by * BM + wm * 64 + i * 16 + q * 4;
#pragma unroll
            for (int jn = 0; jn < 4; ++jn) {
                int col = bx * BN + wn * 64 + jn * 16 + r;
#pragma unroll
                for (int rr = 0; rr < 4; ++rr)
                    Cp[(size_t)(rowb + rr) * ldc + col] = acc[i][jn][rr] * alpha;
            }
        }
    }
}

// fp32 -> bf16 elementwise cast (x). Exact grid: n/1024 blocks.
__global__ void cast_f32_bf16(const float4* __restrict__ in, ushort4* __restrict__ out) {
    int i = blockIdx.x * 256 + threadIdx.x;
    float4 f = in[i];
    ushort4 o;
    o.x = f2bf(f.x); o.y = f2bf(f.y); o.z = f2bf(f.z); o.w = f2bf(f.w);
    out[i] = o;
}

// transpose + cast: in fp32 [R][Cc] -> out bf16 [Cc][R]  (weights, small)
__global__ void transpose_cast_f32(const float* __restrict__ in, u16* __restrict__ out,
                                   int R, int Cc) {
    __shared__ u16 tile[32][33];
    int tx = threadIdx.x, ty = threadIdx.y;
    int c0 = blockIdx.x * 32, r0 = blockIdx.y * 32;
#pragma unroll
    for (int k = 0; k < 4; ++k)
        tile[ty + k * 8][tx] = f2bf(in[(size_t)(r0 + ty + k * 8) * Cc + c0 + tx]);
    __syncthreads();
#pragma unroll
    for (int k = 0; k < 4; ++k)
        out[(size_t)(c0 + ty + k * 8) * R + r0 + tx] = tile[tx][ty + k * 8];
}

// In-place causal softmax on the PACKED-triangular S, one WAVE per row.
// Row t (block-row by=t>>7) has length L=(by+1)*128 fp32 at
// S + z*sS + P(by) + (t&127)*L. Reads fp32 scores [0,t], writes bf16
// probabilities over the same bytes, zero-filling [t+1, L).
__global__ __launch_bounds__(256) void softmax_causal_packed(
    float* __restrict__ S, long long sS)
{
    const int wave = threadIdx.x >> 6, lane = threadIdx.x & 63;
    const int t = blockIdx.x * 4 + wave;
    const int by = t >> 7, lr = t & 127;
    const int L = (by + 1) << 7;
    float* row = S + (long long)blockIdx.y * sS
               + 16384LL * (by * (by + 1) / 2) + (size_t)lr * L;
    const int n = t + 1;
    const int nit = (L + 255) >> 8;        // chunks of 64 lanes x 4 floats, <=8

    float v[32];
    float m = -1e30f;
    for (int it = 0; it < nit; ++it) {
        int c = it * 64 + lane;
        int e = c * 4;
        float4 f = make_float4(-1e30f, -1e30f, -1e30f, -1e30f);
        if (e < n) f = ((const float4*)row)[c];
        v[it * 4 + 0] = (e + 0 < n) ? f.x : -1e30f;
        v[it * 4 + 1] = (e + 1 < n) ? f.y : -1e30f;
        v[it * 4 + 2] = (e + 2 < n) ? f.z : -1e30f;
        v[it * 4 + 3] = (e + 3 < n) ? f.w : -1e30f;
        m = fmaxf(m, fmaxf(fmaxf(v[it * 4 + 0], v[it * 4 + 1]),
                           fmaxf(v[it * 4 + 2], v[it * 4 + 3])));
    }
    for (int off = 32; off > 0; off >>= 1) m = fmaxf(m, __shfl_xor(m, off));

    float s = 0.f;
    for (int it = 0; it < nit; ++it) {
#pragma unroll
        for (int j = 0; j < 4; ++j) {
            v[it * 4 + j] = __expf(v[it * 4 + j] - m);
            s += v[it * 4 + j];
        }
    }
    for (int off = 32; off > 0; off >>= 1) s += __shfl_xor(s, off);
    float inv = 1.f / s;

    u16* orow = (u16*)row;
    for (int it = 0; it < nit; ++it) {
        int c = it * 64 + lane;
        if (c * 4 < L) {
            ushort4 o;
            o.x = f2bf(v[it * 4 + 0] * inv);
            o.y = f2bf(v[it * 4 + 1] * inv);
            o.z = f2bf(v[it * 4 + 2] * inv);
            o.w = f2bf(v[it * 4 + 3] * inv);
            ((ushort4*)orow)[c] = o;
        }
    }
}

extern "C" void kernel_launch(void* const* d_in, const int* in_sizes, int n_in,
                              void* d_out, int out_size, void* d_ws, size_t ws_size,
                              hipStream_t stream)
{
    const float* x     = (const float*)d_in[0];
    const float* Wqkv  = (const float*)d_in[1];
    const float* Wproj = (const float*)d_in[2];
    float* out = (float*)d_out;

    const int Bb = 8, T = 2048, C1 = 1024, C3 = 3072;

    // Reassociation: out = (A@V)@Wp = A@(V@Wp); VWpT[b] = Wp^T@V^T computed
    // right after qkv, replacing the vT transpose AND the final proj GEMM.
    // VWpT overlays xb (dead after qkv); S is packed-triangular (8.9 MB/batch)
    // so the zc=8 high-water mark is 204 MB.
    char* ws = (char*)d_ws;
    u16*  xb     = (u16*)(ws);                       //  32 MB  x bf16 (dead post-qkv)
    u16*  VWpT   = (u16*)(ws);                       //  32 MB  overlay [B][C, T]
    u16*  WqkvT  = (u16*)(ws +  33554432ULL);        //   6 MB  [3C, C]
    u16*  WprojT = (u16*)(ws +  39845888ULL);        //   2 MB  [C, C]
    u16*  qkvb   = (u16*)(ws +  41943040ULL);        //  96 MB  [B*T, 3C]
    float* Sbuf  = (float*)(ws + 142606336ULL);      //  zc * 8.9 MB packed scores

    // largest batch-chunk whose packed score buffer fits the workspace
    const unsigned long long sbytes = SPACK_ELEMS * 4ULL;   // 8,912,896 B/batch
    int zc = 1;
    if      (ws_size >= 142606336ULL + 8ULL * sbytes) zc = 8;
    else if (ws_size >= 142606336ULL + 4ULL * sbytes) zc = 4;
    else if (ws_size >= 142606336ULL + 2ULL * sbytes) zc = 2;

    // 1. cast x -> bf16   (16.7M elems, exact grid)
    cast_f32_bf16<<<16384, 256, 0, stream>>>((const float4*)x, (ushort4*)xb);

    // 2. transpose+cast weights
    transpose_cast_f32<<<dim3(96, 32), dim3(32, 8), 0, stream>>>(Wqkv,  WqkvT,  C1, C3);
    transpose_cast_f32<<<dim3(32, 32), dim3(32, 8), 0, stream>>>(Wproj, WprojT, C1, C1);

    // 3. qkv = x @ Wqkv   [16384,1024]x[1024,3072] -> bf16 [16384,3072]
    gemm_bt<true><<<dim3(24, 128, 1), 256, 0, stream>>>(
        xb, WqkvT, qkvb, C1, C1, C1, C3, 0, 0, 0, 1.0f, 0);

    // 4. VWpT[b] = Wp^T @ V^T : [C1, T] bf16 (writes over dead xb region)
    gemm_bt<true><<<dim3(16, 8, 8), 256, 0, stream>>>(
        WprojT, qkvb + 2 * C1, VWpT, C1, C1, C3, T,
        0, (long long)T * C3, (long long)C1 * T, 1.0f, 0);

    // 5. attention, zc batches at a time
    for (int i = 0; i < Bb; i += zc) {
        const u16* qb   = qkvb + (long long)i * T * C3;
        const u16* kb   = qb + C1;
        const u16* vwpb = VWpT + (long long)i * C1 * T;
        float* ob = out + (long long)i * T * C1;

        // S = (q @ k^T) * C^-0.5, fp32 packed-triangular (136 blocks/batch)
        gemm_bt<false><<<dim3(136, 1, zc), 256, 0, stream>>>(
            qb, kb, Sbuf, C1, C3, C3, 0,
            (long long)T * C3, (long long)T * C3, SPACK_ELEMS,
            0.03125f, 1);

        // A = causal softmax(S), bf16 in place within packed rows
        softmax_causal_packed<<<dim3(T / 4, zc), 256, 0, stream>>>(
            Sbuf, SPACK_ELEMS);

        // out = A @ (V@Wp): A bf16 from packed S, B^T = VWpT [C,T], K kcap'd,
        // by reversed so longest-K blocks dispatch first
        gemm_bt<false><<<dim3(8, 16, zc), 256, 0, stream>>>(
            (const u16*)Sbuf, vwpb, ob, T, 0, T, C1,
            2LL * SPACK_ELEMS, (long long)C1 * T, (long long)T * C1,
            1.0f, 2);
    }

    (void)in_sizes; (void)n_in; (void)out_size;
}